// Round 6
// baseline (450.071 us; speedup 1.0000x reference)
//
#include <hip/hip_runtime.h>

// Attention_85212151153298 — round 18.
// R17 post-mortem: per-element f32 atomics REGRESSED hard (splitk 72.4 us,
// WRITE 65.6 MB, adjacent-block same-line contention). Reverted to R15 base
// (best measured 242.7). Cost audit: Sum(kernels) ~168 us vs 242.7 total ->
// ~75 us of dispatch-boundary gaps. This round removes one dispatch the
// right way: ticket-fused split-K reduction (CK pattern). Splitk writes
// bf16 partials as before (plain stores), then __threadfence + one
// atomicAdd(cnt[tile]); the 4th arriver sums 4 partials + Z -> out for its
// tile (fixed-order f32 = identical numerics to reduce_kernel). cnt zeroed
// by atomicExch in red2 (2 boundaries upstream). Predicted: reduce gone,
// splitk 40 -> 46-50, total 242.7 -> ~225-232.

#define LMBD 0.9f
#define CTXN 4096
#define DIMN 1025
#define DP 1152   // padded leading-dim stride (unchanged)
#define KE 1088   // trimmed K for the e-dimension: 17*64 >= 1025

#define KSPLIT 1024                  // 4 equal splits of 4096
#define PSTRIDE ((size_t)DP * CTXN)  // elements per split-K partial (bf16)

typedef __bf16 bf16x8 __attribute__((ext_vector_type(8)));
typedef float f32x4 __attribute__((ext_vector_type(4)));
typedef long lx2 __attribute__((ext_vector_type(2)));

__device__ __forceinline__ unsigned short f2bf(float f) {
  union { float f; unsigned u; } v; v.f = f;
  unsigned r = v.u + 0x7FFFu + ((v.u >> 16) & 1u);  // RNE
  return (unsigned short)(r >> 16);
}
__device__ __forceinline__ float bf2f(unsigned short h) {
  union { unsigned u; float f; } v; v.u = ((unsigned)h) << 16;
  return v.f;
}

__device__ __forceinline__ void gld_lds16(const void* g, void* l) {
  __builtin_amdgcn_global_load_lds(
      (const __attribute__((address_space(1))) unsigned int*)g,
      (__attribute__((address_space(3))) unsigned int*)l, 16, 0, 0);
}

// ---------------- bf16 NT GEMM body, tile TM x TN, BK=64 -------------------
// C[i,j] = sum_k A[i,k]*B[j,k]; A:(M,K), B:(N,K) bf16 row-major.
// LDS rows 128 B = eight 16 B slots; slot s of row r holds global k-chunk
// (s - (r&7)) & 7 -> each 8-lane read phase covers all 32 banks exactly once
// (R10: conflicts 4.9e6 -> 2.3e5).
// MODE 0: bf16 out. MODE 1: f32 out. MODE 4 (128x128): bf16 out + per-col
// softmax partial stats over the block's 128 rows.
template <int MODE, int TM, int TN>
__device__ __forceinline__ void gemm_body(
    const unsigned short* __restrict__ A, const unsigned short* __restrict__ B,
    void* __restrict__ Cout, int K, int lda, int ldb, int ldc, int bi, int bj,
    float* __restrict__ pmax, float* __restrict__ psum) {
  constexpr int FI = TM / 32, FJ = TN / 32;  // frags per wave
  __shared__ unsigned short sA[TM * 64];
  __shared__ unsigned short sB[TN * 64];
  const int tid = threadIdx.x;
  const int wave = tid >> 6;
  const int lane = tid & 63;
  const long i0 = (long)bi * TM;
  const long j0 = (long)bj * TN;
  const int wm = (wave & 1) * (TM / 2);
  const int wn = (wave >> 1) * (TN / 2);

  f32x4 acc[FI][FJ] = {};

  const int srow8 = lane >> 3;              // row within 8-row gld chunk
  const int gk = ((lane & 7) - srow8) & 7;  // staged global k-chunk
  const int mrow = lane & 15;
  const int q2 = lane >> 4;                 // 0..3

  for (int k0 = 0; k0 < K; k0 += 64) {
    __syncthreads();
#pragma unroll
    for (int c = 0; c < TM / 32; ++c) {
      const int q = wave * (TM / 32) + c;
      gld_lds16(A + (i0 + q * 8 + srow8) * (long)lda + k0 + gk * 8, &sA[q * 512]);
    }
#pragma unroll
    for (int c = 0; c < TN / 32; ++c) {
      const int q = wave * (TN / 32) + c;
      gld_lds16(B + (j0 + q * 8 + srow8) * (long)ldb + k0 + gk * 8, &sB[q * 512]);
    }
    __syncthreads();
#pragma unroll
    for (int kk = 0; kk < 2; ++kk) {
      const int slot = ((kk * 4 + q2) + mrow) & 7;
      bf16x8 af[FI], bfr[FJ];
#pragma unroll
      for (int i = 0; i < FI; ++i)
        af[i] = *(const bf16x8*)&sA[(wm + i * 16 + mrow) * 64 + slot * 8];
#pragma unroll
      for (int j = 0; j < FJ; ++j)
        bfr[j] = *(const bf16x8*)&sB[(wn + j * 16 + mrow) * 64 + slot * 8];
#pragma unroll
      for (int i = 0; i < FI; ++i)
#pragma unroll
        for (int j = 0; j < FJ; ++j)
          acc[i][j] =
              __builtin_amdgcn_mfma_f32_16x16x32_bf16(af[i], bfr[j], acc[i][j], 0, 0, 0);
    }
  }

  const int lr = (lane >> 4) * 4;
  const int lc = lane & 15;
#pragma unroll
  for (int i = 0; i < FI; ++i) {
#pragma unroll
    for (int j = 0; j < FJ; ++j) {
#pragma unroll
      for (int r = 0; r < 4; ++r) {
        const long row = i0 + wm + i * 16 + lr + r;
        const long col = j0 + wn + j * 16 + lc;
        const float v = acc[i][j][r];
        if (MODE == 1) ((float*)Cout)[row * ldc + col] = v;
        else ((unsigned short*)Cout)[row * ldc + col] = f2bf(v);
      }
    }
  }

  if constexpr (MODE == 4) {
    float* sMax = (float*)sA;  // [128][8]
    float* sSum = (float*)sB;
    const int k8 = (wave & 1) * 4 + (lane >> 4);
    __syncthreads();
#pragma unroll
    for (int j = 0; j < FJ; ++j) {
      float m = -1e30f;
#pragma unroll
      for (int i = 0; i < FI; ++i)
#pragma unroll
        for (int r = 0; r < 4; ++r) m = fmaxf(m, acc[i][j][r]);
      float sv = 0.f;
#pragma unroll
      for (int i = 0; i < FI; ++i)
#pragma unroll
        for (int r = 0; r < 4; ++r) sv += __expf(acc[i][j][r] - m);
      const int c = wn + j * 16 + lc;
      sMax[c * 8 + k8] = m;
      sSum[c * 8 + k8] = sv;
    }
    __syncthreads();
    if (tid < 128) {
      float m = -1e30f;
#pragma unroll
      for (int k = 0; k < 8; ++k) m = fmaxf(m, sMax[tid * 8 + k]);
      float sv = 0.f;
#pragma unroll
      for (int k = 0; k < 8; ++k) sv += sSum[tid * 8 + k] * __expf(sMax[tid * 8 + k] - m);
      pmax[(size_t)bi * CTXN + j0 + tid] = m;
      psum[(size_t)bi * CTXN + j0 + tid] = sv;
    }
  }
}

// XT[m,n] = sum_d QZT[m,d]*ZbT[n,d] (K=1088) + per-col stats. grid (32,32).
__global__ __launch_bounds__(256, 4) void gemm_xt(
    const unsigned short* __restrict__ QZT, const unsigned short* __restrict__ ZbT,
    unsigned short* __restrict__ XT, float* __restrict__ pmax,
    float* __restrict__ psum) {
  gemm_body<4, 128, 128>(QZT, ZbT, XT, KE, DP, DP, CTXN, blockIdx.x, blockIdx.y, pmax,
                         psum);
}

// Merged QZT + PZ dispatch, 1088 blocks (4.25/CU), K=1088, half-tiles.
__global__ __launch_bounds__(256, 2) void gemm_dual(
    const unsigned short* __restrict__ ZbT, const unsigned short* __restrict__ Qb,
    unsigned short* __restrict__ QZT, const unsigned short* __restrict__ Pb,
    float* __restrict__ PZ) {
  const unsigned g = blockIdx.x;
  if (g < 544) {
    gemm_body<0, 128, 64>(ZbT, Qb, QZT, KE, DP, DP, DP, g & 31, g >> 5, nullptr,
                          nullptr);
  } else {
    const unsigned h = g - 544;
    gemm_body<1, 64, 128>(Pb, ZbT, PZ, KE, DP, DP, CTXN, h >> 5, h & 31, nullptr,
                          nullptr);
  }
}

// ---------------- fp8 NT split-K GEMM + ticket-fused reduction -------------
// A: PZMb (fp8, x256), B: ET (fp8). Partials bf16 (x256) as in R15 (plain
// stores, zero contention). Then one __threadfence + atomicAdd(cnt[tile]);
// the 4th arriver sums the 4 partials + Z and writes out (fixed-order f32 =
// reduce_kernel numerics). grid g = bj + 32*(bi*4 + bz), 1152 blocks.
__global__ __launch_bounds__(256, 2) void gemm_fp8_splitk(
    const unsigned char* __restrict__ A, const unsigned char* __restrict__ B,
    unsigned short* __restrict__ Pt, const float* __restrict__ Z,
    float* __restrict__ Out, unsigned int* __restrict__ cnt) {
  __shared__ unsigned char sA[128 * 64];
  __shared__ unsigned char sB[128 * 64];
  const int tid = threadIdx.x;
  const int wave = tid >> 6;
  const int lane = tid & 63;
  const unsigned g = blockIdx.x;
  const unsigned bj = g & 31;
  const unsigned t = g >> 5;  // 0..35
  const unsigned bi = t >> 2;
  const unsigned bz = t & 3;
  const long i0 = (long)bi * 128;
  const long j0 = (long)bj * 128;
  const int wm = (wave & 1) * 64;
  const int wn = (wave >> 1) * 64;
  const int kb = bz * KSPLIT;
  unsigned short* Pw = Pt + (size_t)bz * PSTRIDE;

  f32x4 acc[4][4] = {};
  const int srow = lane >> 2;
  const int skc = (((lane & 3) - (lane >> 3)) & 3) * 16;  // swizzled 16B slot
  const int mrow = lane & 15;
  const int slot = ((((lane >> 4) + (mrow >> 1)) & 3)) * 16;

  for (int k0 = kb; k0 < kb + KSPLIT; k0 += 64) {
    __syncthreads();
#pragma unroll
    for (int c = 0; c < 2; ++c) {
      const int q = wave * 2 + c;
      gld_lds16(A + (i0 + q * 16 + srow) * (long)CTXN + k0 + skc, &sA[q * 1024]);
      gld_lds16(B + (j0 + q * 16 + srow) * (long)CTXN + k0 + skc, &sB[q * 1024]);
    }
    __syncthreads();
    lx2 af[4], bfr[4];
#pragma unroll
    for (int i = 0; i < 4; ++i)
      af[i] = *(const lx2*)&sA[(wm + i * 16 + mrow) * 64 + slot];
#pragma unroll
    for (int j = 0; j < 4; ++j)
      bfr[j] = *(const lx2*)&sB[(wn + j * 16 + mrow) * 64 + slot];
#pragma unroll
    for (int i = 0; i < 4; ++i)
#pragma unroll
      for (int j = 0; j < 4; ++j) {
        acc[i][j] = __builtin_amdgcn_mfma_f32_16x16x32_fp8_fp8(af[i].x, bfr[j].x,
                                                               acc[i][j], 0, 0, 0);
        acc[i][j] = __builtin_amdgcn_mfma_f32_16x16x32_fp8_fp8(af[i].y, bfr[j].y,
                                                               acc[i][j], 0, 0, 0);
      }
  }

  const int lr = (lane >> 4) * 4;
  const int lc = lane & 15;
#pragma unroll
  for (int i = 0; i < 4; ++i)
#pragma unroll
    for (int j = 0; j < 4; ++j)
#pragma unroll
      for (int r = 0; r < 4; ++r) {
        const long row = i0 + wm + i * 16 + lr + r;
        if (row < DIMN)
          Pw[row * (long)CTXN + j0 + wn + j * 16 + lc] = f2bf(acc[i][j][r]);
      }

  // ---- ticket: 4th arriver for this tile reduces partials + Z -> Out ----
  __threadfence();  // release: partial stores visible device-wide
  __syncthreads();  // all threads' fences done before the ticket
  __shared__ unsigned s_old;
  if (tid == 0) s_old = atomicAdd(&cnt[bi * 32 + bj], 1u);
  __syncthreads();
  if (s_old == 3u) {
    __threadfence();  // acquire: see the other splits' partials
#pragma unroll
    for (int e = 0; e < 16; ++e) {
      const int idx4 = e * 256 + tid;  // 0..4095 float4s of the 128x128 tile
      const int r = idx4 >> 5;         // row in tile (32 float4 per row)
      const int c = (idx4 & 31) * 4;
      const long row = i0 + r;
      if (row < DIMN) {
        const size_t base = (size_t)row * CTXN + j0 + c;
        const f32x4 zv = *(const f32x4*)&Z[base];
        float a0 = 0.f, a1 = 0.f, a2 = 0.f, a3 = 0.f;
#pragma unroll
        for (int z = 0; z < 4; ++z) {
          const ushort4 v = *(const ushort4*)&Pt[(size_t)z * PSTRIDE + base];
          a0 += bf2f(v.x); a1 += bf2f(v.y); a2 += bf2f(v.z); a3 += bf2f(v.w);
        }
        f32x4 o;
        o[0] = zv[0] + a0 * 0.00390625f;
        o[1] = zv[1] + a1 * 0.00390625f;
        o[2] = zv[2] + a2 * 0.00390625f;
        o[3] = zv[3] + a3 * 0.00390625f;
        *(f32x4*)&Out[base] = o;
      }
    }
  }
}

// Merged prep: ids [0,4352) transpose Z -> ZbT (e < 1088 only; rest unused);
// ids [4352, 6944) pad Q/P -> Qb/Pb bf16 (full 1152x1152, zeros outside).
__global__ void prep_kernel(const float* __restrict__ Z, const float* __restrict__ Q,
                            const float* __restrict__ P,
                            unsigned short* __restrict__ ZbT,
                            unsigned short* __restrict__ Qb,
                            unsigned short* __restrict__ Pb) {
  __shared__ float tile[32][33];
  const unsigned g = blockIdx.x;
  const int tid = threadIdx.x;
  if (g < 4352) {
    const int n0 = (g & 127) * 32, e0 = (g >> 7) * 32;  // e0 < 1088
    const int tx = tid & 31, ty = tid >> 5;
#pragma unroll
    for (int k = 0; k < 4; ++k) {
      const int e = e0 + ty + k * 8;
      tile[ty + k * 8][tx] = (e < DIMN) ? Z[(size_t)e * CTXN + n0 + tx] : 0.f;
    }
    __syncthreads();
#pragma unroll
    for (int k = 0; k < 4; ++k) {
      const int n = n0 + ty + k * 8;
      ZbT[(size_t)n * DP + e0 + tx] = f2bf(tile[tx][ty + k * 8]);
    }
  } else {
    const unsigned id2 = g - 4352;  // [0, 2592)
    const int mat = id2 >= 1296;
    const float* src = mat ? P : Q;
    unsigned short* dst = mat ? Pb : Qb;
    const unsigned e0 = (id2 - (mat ? 1296u : 0u)) * 1024u + tid * 4u;
    const unsigned r = e0 / 1152u;
    const unsigned c = e0 - r * 1152u;
    ushort4 o;
    o.x = (r < DIMN && c + 0 < DIMN) ? f2bf(src[(size_t)r * DIMN + c + 0]) : 0;
    o.y = (r < DIMN && c + 1 < DIMN) ? f2bf(src[(size_t)r * DIMN + c + 1]) : 0;
    o.z = (r < DIMN && c + 2 < DIMN) ? f2bf(src[(size_t)r * DIMN + c + 2]) : 0;
    o.w = (r < DIMN && c + 3 < DIMN) ? f2bf(src[(size_t)r * DIMN + c + 3]) : 0;
    *(ushort4*)&dst[(size_t)r * DP + c] = o;
  }
}

// merge 32 chunk stats -> rowmax[n], inv_l[n] = 1/(N*l[n]); zero ticket cnt.
__global__ void red2_kernel(const float* __restrict__ pmax, const float* __restrict__ psum,
                            float* __restrict__ rowmax, float* __restrict__ inv_l,
                            unsigned int* __restrict__ cnt) {
  const int n = blockIdx.x * 256 + threadIdx.x;
  if (n < 288) atomicExch(&cnt[n], 0u);  // atomic: visible to splitk's RMWs
  float M = -1e30f;
  for (int c = 0; c < 32; ++c) M = fmaxf(M, pmax[(size_t)c * CTXN + n]);
  float s = 0.f;
  for (int c = 0; c < 32; ++c)
    s += psum[(size_t)c * CTXN + n] * __expf(pmax[(size_t)c * CTXN + n] - M);
  rowmax[n] = M;
  inv_l[n] = 1.0f / (4095.0f * s);
}

// Merged ew + scan. ids [0,1088): suffix lambda-scan of PZ row d -> PZMb fp8 x256.
// ids [1088, 17472): ET[m][n] = fp8(exp(XT[m][n] - rowmax[n])).
__global__ __launch_bounds__(256) void ewscan_kernel(
    const unsigned short* __restrict__ XT, const float* __restrict__ rowmax,
    unsigned int* __restrict__ ET, const float* __restrict__ PZ,
    const float* __restrict__ inv_l, unsigned char* __restrict__ PZMb) {
  __shared__ float sF[256];
  const unsigned g = blockIdx.x;
  const int t = threadIdx.x;
  if (g >= 1088) {
    const size_t idx = ((size_t)(g - 1088) * 256 + t) * 4;
    const ushort4 v = *(const ushort4*)&XT[idx];
    const int n = (int)(idx & 4095);
    const float4 rm = *(const float4*)&rowmax[n];
    unsigned p = __builtin_amdgcn_cvt_pk_fp8_f32(__expf(bf2f(v.x) - rm.x),
                                                 __expf(bf2f(v.y) - rm.y), 0, false);
    p = __builtin_amdgcn_cvt_pk_fp8_f32(__expf(bf2f(v.z) - rm.z),
                                        __expf(bf2f(v.w) - rm.w), p, true);
    ET[idx >> 2] = p;
    return;
  }
  const int d = g;
  const float* row = PZ + (size_t)d * CTXN;
  float x[16];
#pragma unroll
  for (int q = 0; q < 4; ++q) {
    const float4 v = *(const float4*)&row[t * 16 + q * 4];
    x[q * 4 + 0] = v.x; x[q * 4 + 1] = v.y; x[q * 4 + 2] = v.z; x[q * 4 + 3] = v.w;
  }
  if (t == 255) x[15] = 0.f;  // last row/col of M are zero
  float loc[16];
  float run = 0.f;
#pragma unroll
  for (int i = 15; i >= 0; --i) { run = run * LMBD + x[i]; loc[i] = run; }
  float f = loc[0];
  sF[t] = f;
  __syncthreads();
  float mlt = 0.1853020188851841f;  // lambda^16
  for (int step = 1; step < 256; step <<= 1) {
    const float other = (t + step < 256) ? sF[t + step] : 0.f;
    __syncthreads();
    f += mlt * other;
    mlt *= mlt;
    sF[t] = f;
    __syncthreads();
  }
  const float R = (t < 255) ? sF[t + 1] : 0.f;
  float il[16];
#pragma unroll
  for (int q = 0; q < 4; ++q) {
    const float4 v = *(const float4*)&inv_l[t * 16 + q * 4];
    il[q * 4 + 0] = v.x * 256.f; il[q * 4 + 1] = v.y * 256.f;
    il[q * 4 + 2] = v.z * 256.f; il[q * 4 + 3] = v.w * 256.f;
  }
  float o[16];
  float p = 1.f;
#pragma unroll
  for (int i = 15; i >= 0; --i) {
    p *= LMBD;
    o[i] = (loc[i] + p * R) * il[i];
  }
  unsigned w[4];
#pragma unroll
  for (int q = 0; q < 4; ++q) {
    unsigned pk = __builtin_amdgcn_cvt_pk_fp8_f32(o[q * 4 + 0], o[q * 4 + 1], 0, false);
    pk = __builtin_amdgcn_cvt_pk_fp8_f32(o[q * 4 + 2], o[q * 4 + 3], pk, true);
    w[q] = pk;
  }
  *(uint4*)&PZMb[(size_t)d * CTXN + t * 16] = make_uint4(w[0], w[1], w[2], w[3]);
}

extern "C" void kernel_launch(void* const* d_in, const int* in_sizes, int n_in,
                              void* d_out, int out_size, void* d_ws, size_t ws_size,
                              hipStream_t stream) {
  const float* Z = (const float*)d_in[0];
  const float* P = (const float*)d_in[1];
  const float* Q = (const float*)d_in[2];
  // d_in[3] = M: reproduced analytically by the scan.

  char* ws = (char*)d_ws;
  size_t off = 0;
  auto alloc = [&](size_t bytes) {
    void* p = ws + off;
    off += (bytes + 255) & ~(size_t)255;
    return p;
  };
  // persistent through the final GEMM:
  unsigned char* ET   = (unsigned char*)alloc((size_t)CTXN * CTXN);  // fp8
  unsigned char* PZMb = (unsigned char*)alloc((size_t)DP * CTXN);    // fp8 x256
  float* rowmax       = (float*)alloc((size_t)CTXN * 4);
  float* inv_l        = (float*)alloc((size_t)CTXN * 4);
  unsigned int* cnt   = (unsigned int*)alloc(288 * 4);
  // pool — ZbT/QZT/XT are dead before the fp8 GEMM; its bf16 partial buffer
  // (4*DP*CTXN*2 = 37.7 MB) overlays them (52.4 MB). PZ untouched.
  char* pool = (char*)alloc(0);
  unsigned short* ZbT = (unsigned short*)alloc((size_t)CTXN * DP * 2);
  unsigned short* QZT = (unsigned short*)alloc((size_t)CTXN * DP * 2);
  unsigned short* XT  = (unsigned short*)alloc((size_t)CTXN * CTXN * 2);
  float* PZ           = (float*)alloc((size_t)DP * CTXN * 4);
  unsigned short* Qb  = (unsigned short*)alloc((size_t)DP * DP * 2);
  unsigned short* Pb  = (unsigned short*)alloc((size_t)DP * DP * 2);
  float* pmax         = (float*)alloc((size_t)32 * CTXN * 4);
  float* psum         = (float*)alloc((size_t)32 * CTXN * 4);
  unsigned short* partials = (unsigned short*)pool;
  if (off > ws_size) return;

  float* out = (float*)d_out;

  // Z transpose (e < 1088) + Q/P pad, one dispatch
  prep_kernel<<<6944, 256, 0, stream>>>(Z, Q, P, ZbT, Qb, Pb);

  // QZT[m,d] and PZ[d,n] in one dispatch, K=1088, half-tiles, 1088 blocks
  gemm_dual<<<1088, 256, 0, stream>>>(ZbT, Qb, QZT, Pb, PZ);

  // XT[m,n] = sum_d QZT[m,d] * ZbT[n,d], K=1088; epilogue: per-col stats
  gemm_xt<<<dim3(32, 32), 256, 0, stream>>>(QZT, ZbT, XT, pmax, psum);

  // rowmax/inv_l + zero the 288 ticket counters
  red2_kernel<<<16, 256, 0, stream>>>(pmax, psum, rowmax, inv_l, cnt);

  // scan (PZ rows < 1088 -> PZMb fp8 x256) + ew (XT -> ET fp8), one dispatch
  ewscan_kernel<<<17472, 256, 0, stream>>>(XT, rowmax, (unsigned int*)ET, PZ, inv_l,
                                           PZMb);

  // partial[z][d,m] = sum_{n in split z}; 4th arriver reduces tile -> out
  gemm_fp8_splitk<<<1152, 256, 0, stream>>>(PZMb, ET, partials, Z, out, cnt);
}

// Round 7
// 248.864 us; speedup vs baseline: 1.8085x; 1.8085x over previous
//
#include <hip/hip_runtime.h>

// Attention_85212151153298 — round 19.
// R18 post-mortem: ticket-fused reduction CATASTROPHIC (450 us; splitk 260
// us, MfmaUtil 5.9%). Per-block __threadfence (device fence -> L2 writeback
// on 8-XCD part) serialized the dispatch. RULE: no per-block device fences;
// cross-dispatch reduction is cheaper than any in-kernel coherence. R17's
// atomics and R18's tickets both refuted -> dispatch structure is final.
// This round = R15 base + one safe parameter change: split-K 4->2 (KSPLIT
// 2048) while KEEPING 1152 blocks via 128x64 output tiles (9 x 64 x 2).
// Halves partial traffic (37.7 -> 18.9 MB each way, ~6-7 us) at +50%
// staging-per-FLOP in a kernel that isn't staging-bound. ET-strip sharers
// at stride 128 = 0 mod 8 -> one XCD (R15 swizzle preserved).
// Predicted: splitk 40->40-44, reduce 14->10, total 242.7 -> ~234-238.

#define LMBD 0.9f
#define CTXN 4096
#define DIMN 1025
#define DP 1152   // padded leading-dim stride (unchanged)
#define KE 1088   // trimmed K for the e-dimension: 17*64 >= 1025

#define KSPLIT 2048                  // 2 equal splits of 4096
#define PSTRIDE ((size_t)DP * CTXN)  // elements per split-K partial (bf16)

typedef __bf16 bf16x8 __attribute__((ext_vector_type(8)));
typedef float f32x4 __attribute__((ext_vector_type(4)));
typedef long lx2 __attribute__((ext_vector_type(2)));

__device__ __forceinline__ unsigned short f2bf(float f) {
  union { float f; unsigned u; } v; v.f = f;
  unsigned r = v.u + 0x7FFFu + ((v.u >> 16) & 1u);  // RNE
  return (unsigned short)(r >> 16);
}
__device__ __forceinline__ float bf2f(unsigned short h) {
  union { unsigned u; float f; } v; v.u = ((unsigned)h) << 16;
  return v.f;
}

__device__ __forceinline__ void gld_lds16(const void* g, void* l) {
  __builtin_amdgcn_global_load_lds(
      (const __attribute__((address_space(1))) unsigned int*)g,
      (__attribute__((address_space(3))) unsigned int*)l, 16, 0, 0);
}

// ---------------- bf16 NT GEMM body, tile TM x TN, BK=64 -------------------
// C[i,j] = sum_k A[i,k]*B[j,k]; A:(M,K), B:(N,K) bf16 row-major.
// LDS rows 128 B = eight 16 B slots; slot s of row r holds global k-chunk
// (s - (r&7)) & 7 -> each 8-lane read phase covers all 32 banks exactly once
// (R10: conflicts 4.9e6 -> 2.3e5).
// MODE 0: bf16 out. MODE 1: f32 out. MODE 4 (128x128): bf16 out + per-col
// softmax partial stats over the block's 128 rows.
template <int MODE, int TM, int TN>
__device__ __forceinline__ void gemm_body(
    const unsigned short* __restrict__ A, const unsigned short* __restrict__ B,
    void* __restrict__ Cout, int K, int lda, int ldb, int ldc, int bi, int bj,
    float* __restrict__ pmax, float* __restrict__ psum) {
  constexpr int FI = TM / 32, FJ = TN / 32;  // frags per wave
  __shared__ unsigned short sA[TM * 64];
  __shared__ unsigned short sB[TN * 64];
  const int tid = threadIdx.x;
  const int wave = tid >> 6;
  const int lane = tid & 63;
  const long i0 = (long)bi * TM;
  const long j0 = (long)bj * TN;
  const int wm = (wave & 1) * (TM / 2);
  const int wn = (wave >> 1) * (TN / 2);

  f32x4 acc[FI][FJ] = {};

  const int srow8 = lane >> 3;              // row within 8-row gld chunk
  const int gk = ((lane & 7) - srow8) & 7;  // staged global k-chunk
  const int mrow = lane & 15;
  const int q2 = lane >> 4;                 // 0..3

  for (int k0 = 0; k0 < K; k0 += 64) {
    __syncthreads();
#pragma unroll
    for (int c = 0; c < TM / 32; ++c) {
      const int q = wave * (TM / 32) + c;
      gld_lds16(A + (i0 + q * 8 + srow8) * (long)lda + k0 + gk * 8, &sA[q * 512]);
    }
#pragma unroll
    for (int c = 0; c < TN / 32; ++c) {
      const int q = wave * (TN / 32) + c;
      gld_lds16(B + (j0 + q * 8 + srow8) * (long)ldb + k0 + gk * 8, &sB[q * 512]);
    }
    __syncthreads();
#pragma unroll
    for (int kk = 0; kk < 2; ++kk) {
      const int slot = ((kk * 4 + q2) + mrow) & 7;
      bf16x8 af[FI], bfr[FJ];
#pragma unroll
      for (int i = 0; i < FI; ++i)
        af[i] = *(const bf16x8*)&sA[(wm + i * 16 + mrow) * 64 + slot * 8];
#pragma unroll
      for (int j = 0; j < FJ; ++j)
        bfr[j] = *(const bf16x8*)&sB[(wn + j * 16 + mrow) * 64 + slot * 8];
#pragma unroll
      for (int i = 0; i < FI; ++i)
#pragma unroll
        for (int j = 0; j < FJ; ++j)
          acc[i][j] =
              __builtin_amdgcn_mfma_f32_16x16x32_bf16(af[i], bfr[j], acc[i][j], 0, 0, 0);
    }
  }

  const int lr = (lane >> 4) * 4;
  const int lc = lane & 15;
#pragma unroll
  for (int i = 0; i < FI; ++i) {
#pragma unroll
    for (int j = 0; j < FJ; ++j) {
#pragma unroll
      for (int r = 0; r < 4; ++r) {
        const long row = i0 + wm + i * 16 + lr + r;
        const long col = j0 + wn + j * 16 + lc;
        const float v = acc[i][j][r];
        if (MODE == 1) ((float*)Cout)[row * ldc + col] = v;
        else ((unsigned short*)Cout)[row * ldc + col] = f2bf(v);
      }
    }
  }

  if constexpr (MODE == 4) {
    float* sMax = (float*)sA;  // [128][8]
    float* sSum = (float*)sB;
    const int k8 = (wave & 1) * 4 + (lane >> 4);
    __syncthreads();
#pragma unroll
    for (int j = 0; j < FJ; ++j) {
      float m = -1e30f;
#pragma unroll
      for (int i = 0; i < FI; ++i)
#pragma unroll
        for (int r = 0; r < 4; ++r) m = fmaxf(m, acc[i][j][r]);
      float sv = 0.f;
#pragma unroll
      for (int i = 0; i < FI; ++i)
#pragma unroll
        for (int r = 0; r < 4; ++r) sv += __expf(acc[i][j][r] - m);
      const int c = wn + j * 16 + lc;
      sMax[c * 8 + k8] = m;
      sSum[c * 8 + k8] = sv;
    }
    __syncthreads();
    if (tid < 128) {
      float m = -1e30f;
#pragma unroll
      for (int k = 0; k < 8; ++k) m = fmaxf(m, sMax[tid * 8 + k]);
      float sv = 0.f;
#pragma unroll
      for (int k = 0; k < 8; ++k) sv += sSum[tid * 8 + k] * __expf(sMax[tid * 8 + k] - m);
      pmax[(size_t)bi * CTXN + j0 + tid] = m;
      psum[(size_t)bi * CTXN + j0 + tid] = sv;
    }
  }
}

// XT[m,n] = sum_d QZT[m,d]*ZbT[n,d] (K=1088) + per-col stats. grid (32,32).
__global__ __launch_bounds__(256, 4) void gemm_xt(
    const unsigned short* __restrict__ QZT, const unsigned short* __restrict__ ZbT,
    unsigned short* __restrict__ XT, float* __restrict__ pmax,
    float* __restrict__ psum) {
  gemm_body<4, 128, 128>(QZT, ZbT, XT, KE, DP, DP, CTXN, blockIdx.x, blockIdx.y, pmax,
                         psum);
}

// Merged QZT + PZ dispatch, 1088 blocks (4.25/CU), K=1088, half-tiles.
__global__ __launch_bounds__(256, 2) void gemm_dual(
    const unsigned short* __restrict__ ZbT, const unsigned short* __restrict__ Qb,
    unsigned short* __restrict__ QZT, const unsigned short* __restrict__ Pb,
    float* __restrict__ PZ) {
  const unsigned g = blockIdx.x;
  if (g < 544) {
    gemm_body<0, 128, 64>(ZbT, Qb, QZT, KE, DP, DP, DP, g & 31, g >> 5, nullptr,
                          nullptr);
  } else {
    const unsigned h = g - 544;
    gemm_body<1, 64, 128>(Pb, ZbT, PZ, KE, DP, DP, CTXN, h >> 5, h & 31, nullptr,
                          nullptr);
  }
}

// ---------------- fp8 NT split-K GEMM (final), BK=64, bf16 partials --------
// A: PZMb (fp8, x256), B: ET (fp8). Partials bf16 (x256), rows < 1025 only.
// R19: 2 splits of K=2048, output tiles 128x64 -> 9*64*2 = 1152 blocks
// (4.5/CU preserved). grid g = bj + 64*(bi*2 + bz); ET-strip sharers (same
// bj) at stride 128 = 0 mod 8 -> one XCD. PZMb rows >= 1088 are garbage but
// row-independent in MFMA and masked at store (fp8 has no Inf).
__global__ __launch_bounds__(256, 2) void gemm_fp8_splitk(
    const unsigned char* __restrict__ A, const unsigned char* __restrict__ B,
    unsigned short* __restrict__ Cout) {
  __shared__ unsigned char sA[128 * 64];
  __shared__ unsigned char sB[64 * 64];
  const int tid = threadIdx.x;
  const int wave = tid >> 6;
  const int lane = tid & 63;
  const unsigned g = blockIdx.x;
  const unsigned bj = g & 63;  // 64 col tiles of 64
  const unsigned t = g >> 6;   // 0..17
  const unsigned bi = t >> 1;  // 0..8
  const unsigned bz = t & 1;
  const long i0 = (long)bi * 128;
  const long j0 = (long)bj * 64;
  const int wm = (wave & 1) * 64;
  const int wn = (wave >> 1) * 32;
  const int kb = bz * KSPLIT;
  Cout += (size_t)bz * PSTRIDE;

  f32x4 acc[4][2] = {};
  const int srow = lane >> 2;
  const int skc = (((lane & 3) - (lane >> 3)) & 3) * 16;  // swizzled 16B slot
  const int mrow = lane & 15;
  const int slot = ((((lane >> 4) + (mrow >> 1)) & 3)) * 16;

  for (int k0 = kb; k0 < kb + KSPLIT; k0 += 64) {
    __syncthreads();
#pragma unroll
    for (int c = 0; c < 2; ++c) {
      const int q = wave * 2 + c;
      gld_lds16(A + (i0 + q * 16 + srow) * (long)CTXN + k0 + skc, &sA[q * 1024]);
    }
    {
      const int q = wave;  // 4 calls stage all 64 B rows
      gld_lds16(B + (j0 + q * 16 + srow) * (long)CTXN + k0 + skc, &sB[q * 1024]);
    }
    __syncthreads();
    lx2 af[4], bfr[2];
#pragma unroll
    for (int i = 0; i < 4; ++i)
      af[i] = *(const lx2*)&sA[(wm + i * 16 + mrow) * 64 + slot];
#pragma unroll
    for (int j = 0; j < 2; ++j)
      bfr[j] = *(const lx2*)&sB[(wn + j * 16 + mrow) * 64 + slot];
#pragma unroll
    for (int i = 0; i < 4; ++i)
#pragma unroll
      for (int j = 0; j < 2; ++j) {
        acc[i][j] = __builtin_amdgcn_mfma_f32_16x16x32_fp8_fp8(af[i].x, bfr[j].x,
                                                               acc[i][j], 0, 0, 0);
        acc[i][j] = __builtin_amdgcn_mfma_f32_16x16x32_fp8_fp8(af[i].y, bfr[j].y,
                                                               acc[i][j], 0, 0, 0);
      }
  }

  const int lr = (lane >> 4) * 4;
  const int lc = lane & 15;
#pragma unroll
  for (int i = 0; i < 4; ++i)
#pragma unroll
    for (int j = 0; j < 2; ++j)
#pragma unroll
      for (int r = 0; r < 4; ++r) {
        const long row = i0 + wm + i * 16 + lr + r;
        if (row < DIMN)
          Cout[row * (long)CTXN + j0 + wn + j * 16 + lc] = f2bf(acc[i][j][r]);
      }
}

// out[r,c] = Z[r,c] + (sum of 2 bf16 partials)/256, 4100 blocks
__global__ void reduce_kernel(const unsigned short* __restrict__ Pt,
                              const float* __restrict__ Z, float* __restrict__ out) {
  const size_t idx = ((size_t)blockIdx.x * 256 + threadIdx.x) * 4;
  float ax = 0.f, ay = 0.f, az = 0.f, aw = 0.f;
#pragma unroll
  for (int z = 0; z < 2; ++z) {
    const ushort4 v = *(const ushort4*)&Pt[(size_t)z * PSTRIDE + idx];
    ax += bf2f(v.x); ay += bf2f(v.y); az += bf2f(v.z); aw += bf2f(v.w);
  }
  const f32x4 zv = *(const f32x4*)&Z[idx];
  f32x4 o;
  o[0] = zv[0] + ax * 0.00390625f;
  o[1] = zv[1] + ay * 0.00390625f;
  o[2] = zv[2] + az * 0.00390625f;
  o[3] = zv[3] + aw * 0.00390625f;
  *(f32x4*)&out[idx] = o;
}

// Merged prep: ids [0,4352) transpose Z -> ZbT (e < 1088 only; rest unused);
// ids [4352, 6944) pad Q/P -> Qb/Pb bf16 (full 1152x1152, zeros outside).
__global__ void prep_kernel(const float* __restrict__ Z, const float* __restrict__ Q,
                            const float* __restrict__ P,
                            unsigned short* __restrict__ ZbT,
                            unsigned short* __restrict__ Qb,
                            unsigned short* __restrict__ Pb) {
  __shared__ float tile[32][33];
  const unsigned g = blockIdx.x;
  const int tid = threadIdx.x;
  if (g < 4352) {
    const int n0 = (g & 127) * 32, e0 = (g >> 7) * 32;  // e0 < 1088
    const int tx = tid & 31, ty = tid >> 5;
#pragma unroll
    for (int k = 0; k < 4; ++k) {
      const int e = e0 + ty + k * 8;
      tile[ty + k * 8][tx] = (e < DIMN) ? Z[(size_t)e * CTXN + n0 + tx] : 0.f;
    }
    __syncthreads();
#pragma unroll
    for (int k = 0; k < 4; ++k) {
      const int n = n0 + ty + k * 8;
      ZbT[(size_t)n * DP + e0 + tx] = f2bf(tile[tx][ty + k * 8]);
    }
  } else {
    const unsigned id2 = g - 4352;  // [0, 2592)
    const int mat = id2 >= 1296;
    const float* src = mat ? P : Q;
    unsigned short* dst = mat ? Pb : Qb;
    const unsigned e0 = (id2 - (mat ? 1296u : 0u)) * 1024u + tid * 4u;
    const unsigned r = e0 / 1152u;
    const unsigned c = e0 - r * 1152u;
    ushort4 o;
    o.x = (r < DIMN && c + 0 < DIMN) ? f2bf(src[(size_t)r * DIMN + c + 0]) : 0;
    o.y = (r < DIMN && c + 1 < DIMN) ? f2bf(src[(size_t)r * DIMN + c + 1]) : 0;
    o.z = (r < DIMN && c + 2 < DIMN) ? f2bf(src[(size_t)r * DIMN + c + 2]) : 0;
    o.w = (r < DIMN && c + 3 < DIMN) ? f2bf(src[(size_t)r * DIMN + c + 3]) : 0;
    *(ushort4*)&dst[(size_t)r * DP + c] = o;
  }
}

// merge 32 chunk stats -> rowmax[n], inv_l[n] = 1/(N*l[n])
__global__ void red2_kernel(const float* __restrict__ pmax, const float* __restrict__ psum,
                            float* __restrict__ rowmax, float* __restrict__ inv_l) {
  const int n = blockIdx.x * 256 + threadIdx.x;
  float M = -1e30f;
  for (int c = 0; c < 32; ++c) M = fmaxf(M, pmax[(size_t)c * CTXN + n]);
  float s = 0.f;
  for (int c = 0; c < 32; ++c)
    s += psum[(size_t)c * CTXN + n] * __expf(pmax[(size_t)c * CTXN + n] - M);
  rowmax[n] = M;
  inv_l[n] = 1.0f / (4095.0f * s);
}

// Merged ew + scan. ids [0,1088): suffix lambda-scan of PZ row d -> PZMb fp8 x256.
// ids [1088, 17472): ET[m][n] = fp8(exp(XT[m][n] - rowmax[n])).
__global__ __launch_bounds__(256) void ewscan_kernel(
    const unsigned short* __restrict__ XT, const float* __restrict__ rowmax,
    unsigned int* __restrict__ ET, const float* __restrict__ PZ,
    const float* __restrict__ inv_l, unsigned char* __restrict__ PZMb) {
  __shared__ float sF[256];
  const unsigned g = blockIdx.x;
  const int t = threadIdx.x;
  if (g >= 1088) {
    const size_t idx = ((size_t)(g - 1088) * 256 + t) * 4;
    const ushort4 v = *(const ushort4*)&XT[idx];
    const int n = (int)(idx & 4095);
    const float4 rm = *(const float4*)&rowmax[n];
    unsigned p = __builtin_amdgcn_cvt_pk_fp8_f32(__expf(bf2f(v.x) - rm.x),
                                                 __expf(bf2f(v.y) - rm.y), 0, false);
    p = __builtin_amdgcn_cvt_pk_fp8_f32(__expf(bf2f(v.z) - rm.z),
                                        __expf(bf2f(v.w) - rm.w), p, true);
    ET[idx >> 2] = p;
    return;
  }
  const int d = g;
  const float* row = PZ + (size_t)d * CTXN;
  float x[16];
#pragma unroll
  for (int q = 0; q < 4; ++q) {
    const float4 v = *(const float4*)&row[t * 16 + q * 4];
    x[q * 4 + 0] = v.x; x[q * 4 + 1] = v.y; x[q * 4 + 2] = v.z; x[q * 4 + 3] = v.w;
  }
  if (t == 255) x[15] = 0.f;  // last row/col of M are zero
  float loc[16];
  float run = 0.f;
#pragma unroll
  for (int i = 15; i >= 0; --i) { run = run * LMBD + x[i]; loc[i] = run; }
  float f = loc[0];
  sF[t] = f;
  __syncthreads();
  float mlt = 0.1853020188851841f;  // lambda^16
  for (int step = 1; step < 256; step <<= 1) {
    const float other = (t + step < 256) ? sF[t + step] : 0.f;
    __syncthreads();
    f += mlt * other;
    mlt *= mlt;
    sF[t] = f;
    __syncthreads();
  }
  const float R = (t < 255) ? sF[t + 1] : 0.f;
  float il[16];
#pragma unroll
  for (int q = 0; q < 4; ++q) {
    const float4 v = *(const float4*)&inv_l[t * 16 + q * 4];
    il[q * 4 + 0] = v.x * 256.f; il[q * 4 + 1] = v.y * 256.f;
    il[q * 4 + 2] = v.z * 256.f; il[q * 4 + 3] = v.w * 256.f;
  }
  float o[16];
  float p = 1.f;
#pragma unroll
  for (int i = 15; i >= 0; --i) {
    p *= LMBD;
    o[i] = (loc[i] + p * R) * il[i];
  }
  unsigned w[4];
#pragma unroll
  for (int q = 0; q < 4; ++q) {
    unsigned pk = __builtin_amdgcn_cvt_pk_fp8_f32(o[q * 4 + 0], o[q * 4 + 1], 0, false);
    pk = __builtin_amdgcn_cvt_pk_fp8_f32(o[q * 4 + 2], o[q * 4 + 3], pk, true);
    w[q] = pk;
  }
  *(uint4*)&PZMb[(size_t)d * CTXN + t * 16] = make_uint4(w[0], w[1], w[2], w[3]);
}

extern "C" void kernel_launch(void* const* d_in, const int* in_sizes, int n_in,
                              void* d_out, int out_size, void* d_ws, size_t ws_size,
                              hipStream_t stream) {
  const float* Z = (const float*)d_in[0];
  const float* P = (const float*)d_in[1];
  const float* Q = (const float*)d_in[2];
  // d_in[3] = M: reproduced analytically by the scan.

  char* ws = (char*)d_ws;
  size_t off = 0;
  auto alloc = [&](size_t bytes) {
    void* p = ws + off;
    off += (bytes + 255) & ~(size_t)255;
    return p;
  };
  // persistent through the final GEMM:
  unsigned char* ET   = (unsigned char*)alloc((size_t)CTXN * CTXN);  // fp8
  unsigned char* PZMb = (unsigned char*)alloc((size_t)DP * CTXN);    // fp8 x256
  float* rowmax       = (float*)alloc((size_t)CTXN * 4);
  float* inv_l        = (float*)alloc((size_t)CTXN * 4);
  // pool — ZbT/QZT/XT are dead before the fp8 GEMM; its bf16 partial buffer
  // (2*DP*CTXN*2 = 18.9 MB) overlays them (52.4 MB). PZ untouched.
  char* pool = (char*)alloc(0);
  unsigned short* ZbT = (unsigned short*)alloc((size_t)CTXN * DP * 2);
  unsigned short* QZT = (unsigned short*)alloc((size_t)CTXN * DP * 2);
  unsigned short* XT  = (unsigned short*)alloc((size_t)CTXN * CTXN * 2);
  float* PZ           = (float*)alloc((size_t)DP * CTXN * 4);
  unsigned short* Qb  = (unsigned short*)alloc((size_t)DP * DP * 2);
  unsigned short* Pb  = (unsigned short*)alloc((size_t)DP * DP * 2);
  float* pmax         = (float*)alloc((size_t)32 * CTXN * 4);
  float* psum         = (float*)alloc((size_t)32 * CTXN * 4);
  unsigned short* partials = (unsigned short*)pool;
  if (off > ws_size) return;

  // Z transpose (e < 1088) + Q/P pad, one dispatch
  prep_kernel<<<6944, 256, 0, stream>>>(Z, Q, P, ZbT, Qb, Pb);

  // QZT[m,d] and PZ[d,n] in one dispatch, K=1088, half-tiles, 1088 blocks
  gemm_dual<<<1088, 256, 0, stream>>>(ZbT, Qb, QZT, Pb, PZ);

  // XT[m,n] = sum_d QZT[m,d] * ZbT[n,d], K=1088; epilogue: per-col stats
  gemm_xt<<<dim3(32, 32), 256, 0, stream>>>(QZT, ZbT, XT, pmax, psum);

  red2_kernel<<<16, 256, 0, stream>>>(pmax, psum, rowmax, inv_l);

  // scan (PZ rows < 1088 -> PZMb fp8 x256) + ew (XT -> ET fp8), one dispatch
  ewscan_kernel<<<17472, 256, 0, stream>>>(XT, rowmax, (unsigned int*)ET, PZ, inv_l,
                                           PZMb);

  // partial[z][d,m] = sum_{n in split z} PZMb[d,n]*ET[m,n]  (x256, bf16)
  gemm_fp8_splitk<<<1152, 256, 0, stream>>>(PZMb, ET, partials);
  // out = Z + (p0+p1)/256 (rows < 1025)
  reduce_kernel<<<4100, 256, 0, stream>>>(partials, Z, (float*)d_out);
}

// Round 8
// 248.075 us; speedup vs baseline: 1.8143x; 1.0032x over previous
//
#include <hip/hip_runtime.h>

// Attention_85212151153298 — round 20.
// R19 post-mortem: 128x64 splitk tile REGRESSED ~5 us (248.9): 1.5x barrier+
// staging per MFMA outweighed halved partial traffic. Lesson: partial-writing
// splitk is optimal at 128x128/4-split (R15). This round removes the reduce
// dispatch the remaining safe way: NO split-K at all. 64x64 tiles -> 17x64 =
// 1088 blocks (proven grid), 8 KB LDS -> all blocks co-resident (8/CU slots,
// 2048 > 1088) -> zero tail, deep cross-block overlap hides the worse
// barrier ratio. Full K=4096 per block, f32 acc, out = Z + acc/256 written
// directly (better numerics than bf16 partials). Partials+reduce gone
// (-55 MB HBM, -1 dispatch). Same-bj sharers at stride 64 = 0 mod 8 -> one
// XCD. Predicted: fp8_final 45-52 us, total 242.7 -> ~228-236.

#define LMBD 0.9f
#define CTXN 4096
#define DIMN 1025
#define DP 1152   // padded leading-dim stride (unchanged)
#define KE 1088   // trimmed K for the e-dimension: 17*64 >= 1025

typedef __bf16 bf16x8 __attribute__((ext_vector_type(8)));
typedef float f32x4 __attribute__((ext_vector_type(4)));
typedef long lx2 __attribute__((ext_vector_type(2)));

__device__ __forceinline__ unsigned short f2bf(float f) {
  union { float f; unsigned u; } v; v.f = f;
  unsigned r = v.u + 0x7FFFu + ((v.u >> 16) & 1u);  // RNE
  return (unsigned short)(r >> 16);
}
__device__ __forceinline__ float bf2f(unsigned short h) {
  union { unsigned u; float f; } v; v.u = ((unsigned)h) << 16;
  return v.f;
}

__device__ __forceinline__ void gld_lds16(const void* g, void* l) {
  __builtin_amdgcn_global_load_lds(
      (const __attribute__((address_space(1))) unsigned int*)g,
      (__attribute__((address_space(3))) unsigned int*)l, 16, 0, 0);
}

// ---------------- bf16 NT GEMM body, tile TM x TN, BK=64 -------------------
// C[i,j] = sum_k A[i,k]*B[j,k]; A:(M,K), B:(N,K) bf16 row-major.
// LDS rows 128 B = eight 16 B slots; slot s of row r holds global k-chunk
// (s - (r&7)) & 7 -> each 8-lane read phase covers all 32 banks exactly once
// (R10: conflicts 4.9e6 -> 2.3e5).
// MODE 0: bf16 out. MODE 1: f32 out. MODE 4 (128x128): bf16 out + per-col
// softmax partial stats over the block's 128 rows.
template <int MODE, int TM, int TN>
__device__ __forceinline__ void gemm_body(
    const unsigned short* __restrict__ A, const unsigned short* __restrict__ B,
    void* __restrict__ Cout, int K, int lda, int ldb, int ldc, int bi, int bj,
    float* __restrict__ pmax, float* __restrict__ psum) {
  constexpr int FI = TM / 32, FJ = TN / 32;  // frags per wave
  __shared__ unsigned short sA[TM * 64];
  __shared__ unsigned short sB[TN * 64];
  const int tid = threadIdx.x;
  const int wave = tid >> 6;
  const int lane = tid & 63;
  const long i0 = (long)bi * TM;
  const long j0 = (long)bj * TN;
  const int wm = (wave & 1) * (TM / 2);
  const int wn = (wave >> 1) * (TN / 2);

  f32x4 acc[FI][FJ] = {};

  const int srow8 = lane >> 3;              // row within 8-row gld chunk
  const int gk = ((lane & 7) - srow8) & 7;  // staged global k-chunk
  const int mrow = lane & 15;
  const int q2 = lane >> 4;                 // 0..3

  for (int k0 = 0; k0 < K; k0 += 64) {
    __syncthreads();
#pragma unroll
    for (int c = 0; c < TM / 32; ++c) {
      const int q = wave * (TM / 32) + c;
      gld_lds16(A + (i0 + q * 8 + srow8) * (long)lda + k0 + gk * 8, &sA[q * 512]);
    }
#pragma unroll
    for (int c = 0; c < TN / 32; ++c) {
      const int q = wave * (TN / 32) + c;
      gld_lds16(B + (j0 + q * 8 + srow8) * (long)ldb + k0 + gk * 8, &sB[q * 512]);
    }
    __syncthreads();
#pragma unroll
    for (int kk = 0; kk < 2; ++kk) {
      const int slot = ((kk * 4 + q2) + mrow) & 7;
      bf16x8 af[FI], bfr[FJ];
#pragma unroll
      for (int i = 0; i < FI; ++i)
        af[i] = *(const bf16x8*)&sA[(wm + i * 16 + mrow) * 64 + slot * 8];
#pragma unroll
      for (int j = 0; j < FJ; ++j)
        bfr[j] = *(const bf16x8*)&sB[(wn + j * 16 + mrow) * 64 + slot * 8];
#pragma unroll
      for (int i = 0; i < FI; ++i)
#pragma unroll
        for (int j = 0; j < FJ; ++j)
          acc[i][j] =
              __builtin_amdgcn_mfma_f32_16x16x32_bf16(af[i], bfr[j], acc[i][j], 0, 0, 0);
    }
  }

  const int lr = (lane >> 4) * 4;
  const int lc = lane & 15;
#pragma unroll
  for (int i = 0; i < FI; ++i) {
#pragma unroll
    for (int j = 0; j < FJ; ++j) {
#pragma unroll
      for (int r = 0; r < 4; ++r) {
        const long row = i0 + wm + i * 16 + lr + r;
        const long col = j0 + wn + j * 16 + lc;
        const float v = acc[i][j][r];
        if (MODE == 1) ((float*)Cout)[row * ldc + col] = v;
        else ((unsigned short*)Cout)[row * ldc + col] = f2bf(v);
      }
    }
  }

  if constexpr (MODE == 4) {
    float* sMax = (float*)sA;  // [128][8]
    float* sSum = (float*)sB;
    const int k8 = (wave & 1) * 4 + (lane >> 4);
    __syncthreads();
#pragma unroll
    for (int j = 0; j < FJ; ++j) {
      float m = -1e30f;
#pragma unroll
      for (int i = 0; i < FI; ++i)
#pragma unroll
        for (int r = 0; r < 4; ++r) m = fmaxf(m, acc[i][j][r]);
      float sv = 0.f;
#pragma unroll
      for (int i = 0; i < FI; ++i)
#pragma unroll
        for (int r = 0; r < 4; ++r) sv += __expf(acc[i][j][r] - m);
      const int c = wn + j * 16 + lc;
      sMax[c * 8 + k8] = m;
      sSum[c * 8 + k8] = sv;
    }
    __syncthreads();
    if (tid < 128) {
      float m = -1e30f;
#pragma unroll
      for (int k = 0; k < 8; ++k) m = fmaxf(m, sMax[tid * 8 + k]);
      float sv = 0.f;
#pragma unroll
      for (int k = 0; k < 8; ++k) sv += sSum[tid * 8 + k] * __expf(sMax[tid * 8 + k] - m);
      pmax[(size_t)bi * CTXN + j0 + tid] = m;
      psum[(size_t)bi * CTXN + j0 + tid] = sv;
    }
  }
}

// XT[m,n] = sum_d QZT[m,d]*ZbT[n,d] (K=1088) + per-col stats. grid (32,32).
__global__ __launch_bounds__(256, 4) void gemm_xt(
    const unsigned short* __restrict__ QZT, const unsigned short* __restrict__ ZbT,
    unsigned short* __restrict__ XT, float* __restrict__ pmax,
    float* __restrict__ psum) {
  gemm_body<4, 128, 128>(QZT, ZbT, XT, KE, DP, DP, CTXN, blockIdx.x, blockIdx.y, pmax,
                         psum);
}

// Merged QZT + PZ dispatch, 1088 blocks (4.25/CU), K=1088, half-tiles.
__global__ __launch_bounds__(256, 2) void gemm_dual(
    const unsigned short* __restrict__ ZbT, const unsigned short* __restrict__ Qb,
    unsigned short* __restrict__ QZT, const unsigned short* __restrict__ Pb,
    float* __restrict__ PZ) {
  const unsigned g = blockIdx.x;
  if (g < 544) {
    gemm_body<0, 128, 64>(ZbT, Qb, QZT, KE, DP, DP, DP, g & 31, g >> 5, nullptr,
                          nullptr);
  } else {
    const unsigned h = g - 544;
    gemm_body<1, 64, 128>(Pb, ZbT, PZ, KE, DP, DP, CTXN, h >> 5, h & 31, nullptr,
                          nullptr);
  }
}

// ---------------- fp8 NT GEMM, no split-K, direct f32 out ------------------
// A: PZMb (fp8, x256, rows 0..1087 valid — rows 1025..1087 are true zeros),
// B: ET (fp8). 64x64 tiles, K=4096, f32 acc, out = Z + acc/256 (rows<1025).
// grid g = bj + 64*bi, 1088 blocks; 8 KB LDS -> all blocks co-resident.
// Same-bj (ET strip) sharers at stride 64 = 0 mod 8 -> one XCD.
__global__ __launch_bounds__(256, 2) void gemm_fp8_final(
    const unsigned char* __restrict__ A, const unsigned char* __restrict__ B,
    const float* __restrict__ Z, float* __restrict__ Out) {
  __shared__ unsigned char sA[64 * 64];
  __shared__ unsigned char sB[64 * 64];
  const int tid = threadIdx.x;
  const int wave = tid >> 6;
  const int lane = tid & 63;
  const unsigned g = blockIdx.x;
  const unsigned bj = g & 63;  // 64 col tiles of 64
  const unsigned bi = g >> 6;  // 0..16
  const long i0 = (long)bi * 64;
  const long j0 = (long)bj * 64;
  const int wm = (wave & 1) * 32;
  const int wn = (wave >> 1) * 32;

  f32x4 acc[2][2] = {};
  const int srow = lane >> 2;
  const int skc = (((lane & 3) - (lane >> 3)) & 3) * 16;  // swizzled 16B slot
  const int mrow = lane & 15;
  const int slot = ((((lane >> 4) + (mrow >> 1)) & 3)) * 16;

  for (int k0 = 0; k0 < CTXN; k0 += 64) {
    __syncthreads();
    gld_lds16(A + (i0 + wave * 16 + srow) * (long)CTXN + k0 + skc, &sA[wave * 1024]);
    gld_lds16(B + (j0 + wave * 16 + srow) * (long)CTXN + k0 + skc, &sB[wave * 1024]);
    __syncthreads();
    lx2 af[2], bfr[2];
#pragma unroll
    for (int i = 0; i < 2; ++i)
      af[i] = *(const lx2*)&sA[(wm + i * 16 + mrow) * 64 + slot];
#pragma unroll
    for (int j = 0; j < 2; ++j)
      bfr[j] = *(const lx2*)&sB[(wn + j * 16 + mrow) * 64 + slot];
#pragma unroll
    for (int i = 0; i < 2; ++i)
#pragma unroll
      for (int j = 0; j < 2; ++j) {
        acc[i][j] = __builtin_amdgcn_mfma_f32_16x16x32_fp8_fp8(af[i].x, bfr[j].x,
                                                               acc[i][j], 0, 0, 0);
        acc[i][j] = __builtin_amdgcn_mfma_f32_16x16x32_fp8_fp8(af[i].y, bfr[j].y,
                                                               acc[i][j], 0, 0, 0);
      }
  }

  const int lr = (lane >> 4) * 4;
  const int lc = lane & 15;
#pragma unroll
  for (int i = 0; i < 2; ++i)
#pragma unroll
    for (int j = 0; j < 2; ++j)
#pragma unroll
      for (int r = 0; r < 4; ++r) {
        const long row = i0 + wm + i * 16 + lr + r;
        if (row < DIMN) {
          const size_t o = (size_t)row * CTXN + j0 + wn + j * 16 + lc;
          Out[o] = Z[o] + acc[i][j][r] * 0.00390625f;
        }
      }
}

// Merged prep: ids [0,4352) transpose Z -> ZbT (e < 1088 only; rest unused);
// ids [4352, 6944) pad Q/P -> Qb/Pb bf16 (full 1152x1152, zeros outside).
__global__ void prep_kernel(const float* __restrict__ Z, const float* __restrict__ Q,
                            const float* __restrict__ P,
                            unsigned short* __restrict__ ZbT,
                            unsigned short* __restrict__ Qb,
                            unsigned short* __restrict__ Pb) {
  __shared__ float tile[32][33];
  const unsigned g = blockIdx.x;
  const int tid = threadIdx.x;
  if (g < 4352) {
    const int n0 = (g & 127) * 32, e0 = (g >> 7) * 32;  // e0 < 1088
    const int tx = tid & 31, ty = tid >> 5;
#pragma unroll
    for (int k = 0; k < 4; ++k) {
      const int e = e0 + ty + k * 8;
      tile[ty + k * 8][tx] = (e < DIMN) ? Z[(size_t)e * CTXN + n0 + tx] : 0.f;
    }
    __syncthreads();
#pragma unroll
    for (int k = 0; k < 4; ++k) {
      const int n = n0 + ty + k * 8;
      ZbT[(size_t)n * DP + e0 + tx] = f2bf(tile[tx][ty + k * 8]);
    }
  } else {
    const unsigned id2 = g - 4352;  // [0, 2592)
    const int mat = id2 >= 1296;
    const float* src = mat ? P : Q;
    unsigned short* dst = mat ? Pb : Qb;
    const unsigned e0 = (id2 - (mat ? 1296u : 0u)) * 1024u + tid * 4u;
    const unsigned r = e0 / 1152u;
    const unsigned c = e0 - r * 1152u;
    ushort4 o;
    o.x = (r < DIMN && c + 0 < DIMN) ? f2bf(src[(size_t)r * DIMN + c + 0]) : 0;
    o.y = (r < DIMN && c + 1 < DIMN) ? f2bf(src[(size_t)r * DIMN + c + 1]) : 0;
    o.z = (r < DIMN && c + 2 < DIMN) ? f2bf(src[(size_t)r * DIMN + c + 2]) : 0;
    o.w = (r < DIMN && c + 3 < DIMN) ? f2bf(src[(size_t)r * DIMN + c + 3]) : 0;
    *(ushort4*)&dst[(size_t)r * DP + c] = o;
  }
}

// merge 32 chunk stats -> rowmax[n], inv_l[n] = 1/(N*l[n])
__global__ void red2_kernel(const float* __restrict__ pmax, const float* __restrict__ psum,
                            float* __restrict__ rowmax, float* __restrict__ inv_l) {
  const int n = blockIdx.x * 256 + threadIdx.x;
  float M = -1e30f;
  for (int c = 0; c < 32; ++c) M = fmaxf(M, pmax[(size_t)c * CTXN + n]);
  float s = 0.f;
  for (int c = 0; c < 32; ++c)
    s += psum[(size_t)c * CTXN + n] * __expf(pmax[(size_t)c * CTXN + n] - M);
  rowmax[n] = M;
  inv_l[n] = 1.0f / (4095.0f * s);
}

// Merged ew + scan. ids [0,1088): suffix lambda-scan of PZ row d -> PZMb fp8 x256.
// ids [1088, 17472): ET[m][n] = fp8(exp(XT[m][n] - rowmax[n])).
__global__ __launch_bounds__(256) void ewscan_kernel(
    const unsigned short* __restrict__ XT, const float* __restrict__ rowmax,
    unsigned int* __restrict__ ET, const float* __restrict__ PZ,
    const float* __restrict__ inv_l, unsigned char* __restrict__ PZMb) {
  __shared__ float sF[256];
  const unsigned g = blockIdx.x;
  const int t = threadIdx.x;
  if (g >= 1088) {
    const size_t idx = ((size_t)(g - 1088) * 256 + t) * 4;
    const ushort4 v = *(const ushort4*)&XT[idx];
    const int n = (int)(idx & 4095);
    const float4 rm = *(const float4*)&rowmax[n];
    unsigned p = __builtin_amdgcn_cvt_pk_fp8_f32(__expf(bf2f(v.x) - rm.x),
                                                 __expf(bf2f(v.y) - rm.y), 0, false);
    p = __builtin_amdgcn_cvt_pk_fp8_f32(__expf(bf2f(v.z) - rm.z),
                                        __expf(bf2f(v.w) - rm.w), p, true);
    ET[idx >> 2] = p;
    return;
  }
  const int d = g;
  const float* row = PZ + (size_t)d * CTXN;
  float x[16];
#pragma unroll
  for (int q = 0; q < 4; ++q) {
    const float4 v = *(const float4*)&row[t * 16 + q * 4];
    x[q * 4 + 0] = v.x; x[q * 4 + 1] = v.y; x[q * 4 + 2] = v.z; x[q * 4 + 3] = v.w;
  }
  if (t == 255) x[15] = 0.f;  // last row/col of M are zero
  float loc[16];
  float run = 0.f;
#pragma unroll
  for (int i = 15; i >= 0; --i) { run = run * LMBD + x[i]; loc[i] = run; }
  float f = loc[0];
  sF[t] = f;
  __syncthreads();
  float mlt = 0.1853020188851841f;  // lambda^16
  for (int step = 1; step < 256; step <<= 1) {
    const float other = (t + step < 256) ? sF[t + step] : 0.f;
    __syncthreads();
    f += mlt * other;
    mlt *= mlt;
    sF[t] = f;
    __syncthreads();
  }
  const float R = (t < 255) ? sF[t + 1] : 0.f;
  float il[16];
#pragma unroll
  for (int q = 0; q < 4; ++q) {
    const float4 v = *(const float4*)&inv_l[t * 16 + q * 4];
    il[q * 4 + 0] = v.x * 256.f; il[q * 4 + 1] = v.y * 256.f;
    il[q * 4 + 2] = v.z * 256.f; il[q * 4 + 3] = v.w * 256.f;
  }
  float o[16];
  float p = 1.f;
#pragma unroll
  for (int i = 15; i >= 0; --i) {
    p *= LMBD;
    o[i] = (loc[i] + p * R) * il[i];
  }
  unsigned w[4];
#pragma unroll
  for (int q = 0; q < 4; ++q) {
    unsigned pk = __builtin_amdgcn_cvt_pk_fp8_f32(o[q * 4 + 0], o[q * 4 + 1], 0, false);
    pk = __builtin_amdgcn_cvt_pk_fp8_f32(o[q * 4 + 2], o[q * 4 + 3], pk, true);
    w[q] = pk;
  }
  *(uint4*)&PZMb[(size_t)d * CTXN + t * 16] = make_uint4(w[0], w[1], w[2], w[3]);
}

extern "C" void kernel_launch(void* const* d_in, const int* in_sizes, int n_in,
                              void* d_out, int out_size, void* d_ws, size_t ws_size,
                              hipStream_t stream) {
  const float* Z = (const float*)d_in[0];
  const float* P = (const float*)d_in[1];
  const float* Q = (const float*)d_in[2];
  // d_in[3] = M: reproduced analytically by the scan.

  char* ws = (char*)d_ws;
  size_t off = 0;
  auto alloc = [&](size_t bytes) {
    void* p = ws + off;
    off += (bytes + 255) & ~(size_t)255;
    return p;
  };
  // persistent through the final GEMM:
  unsigned char* ET   = (unsigned char*)alloc((size_t)CTXN * CTXN);  // fp8
  unsigned char* PZMb = (unsigned char*)alloc((size_t)DP * CTXN);    // fp8 x256
  float* rowmax       = (float*)alloc((size_t)CTXN * 4);
  float* inv_l        = (float*)alloc((size_t)CTXN * 4);
  unsigned short* ZbT = (unsigned short*)alloc((size_t)CTXN * DP * 2);
  unsigned short* QZT = (unsigned short*)alloc((size_t)CTXN * DP * 2);
  unsigned short* XT  = (unsigned short*)alloc((size_t)CTXN * CTXN * 2);
  float* PZ           = (float*)alloc((size_t)DP * CTXN * 4);
  unsigned short* Qb  = (unsigned short*)alloc((size_t)DP * DP * 2);
  unsigned short* Pb  = (unsigned short*)alloc((size_t)DP * DP * 2);
  float* pmax         = (float*)alloc((size_t)32 * CTXN * 4);
  float* psum         = (float*)alloc((size_t)32 * CTXN * 4);
  if (off > ws_size) return;

  // Z transpose (e < 1088) + Q/P pad, one dispatch
  prep_kernel<<<6944, 256, 0, stream>>>(Z, Q, P, ZbT, Qb, Pb);

  // QZT[m,d] and PZ[d,n] in one dispatch, K=1088, half-tiles, 1088 blocks
  gemm_dual<<<1088, 256, 0, stream>>>(ZbT, Qb, QZT, Pb, PZ);

  // XT[m,n] = sum_d QZT[m,d] * ZbT[n,d], K=1088; epilogue: per-col stats
  gemm_xt<<<dim3(32, 32), 256, 0, stream>>>(QZT, ZbT, XT, pmax, psum);

  red2_kernel<<<16, 256, 0, stream>>>(pmax, psum, rowmax, inv_l);

  // scan (PZ rows < 1088 -> PZMb fp8 x256) + ew (XT -> ET fp8), one dispatch
  ewscan_kernel<<<17472, 256, 0, stream>>>(XT, rowmax, (unsigned int*)ET, PZ, inv_l,
                                           PZMb);

  // out = Z + (PZMb @ ET^T)/256, no split-K, direct f32 (rows < 1025)
  gemm_fp8_final<<<1088, 256, 0, stream>>>(PZMb, ET, Z, (float*)d_out);
}

// Round 9
// 242.919 us; speedup vs baseline: 1.8528x; 1.0212x over previous
//
#include <hip/hip_runtime.h>

// Attention_85212151153298 — round 21.
// R20 post-mortem: no-split fp8_final matched prediction (47 us, MfmaUtil
// 27.7%) but total stayed ~flat -> cross-round algebra (R15/R17/R20) shows
// splitk~30 + reduce~12 and NEARLY-FREE dispatch boundaries (graph capture).
// Fusion direction closed. This round attacks fp8_final's MFMA:barrier
// ratio directly: BK 64 -> 128 (16 MFMA per barrier-pair, LDS 8->16 KB,
// still fully co-resident at 1088 blocks; m132's BK=128 warning applied to
// 64KB-LDS bf16 tiles, not here). Plus PZ f32 -> bf16 (dual MODE 0, ewscan
// bf16 reads): -18 MB HBM; PZ feeds fp8 quantization, bf16 rounding is
// noise. Predicted: fp8_final 47 -> ~38, MfmaUtil -> 36-40%, dual/ewscan
// -1.5 each, total 248.1 -> ~237-241 (new best vs 242.7).

#define LMBD 0.9f
#define CTXN 4096
#define DIMN 1025
#define DP 1152   // padded leading-dim stride (unchanged)
#define KE 1088   // trimmed K for the e-dimension: 17*64 >= 1025

typedef __bf16 bf16x8 __attribute__((ext_vector_type(8)));
typedef float f32x4 __attribute__((ext_vector_type(4)));
typedef long lx2 __attribute__((ext_vector_type(2)));

__device__ __forceinline__ unsigned short f2bf(float f) {
  union { float f; unsigned u; } v; v.f = f;
  unsigned r = v.u + 0x7FFFu + ((v.u >> 16) & 1u);  // RNE
  return (unsigned short)(r >> 16);
}
__device__ __forceinline__ float bf2f(unsigned short h) {
  union { unsigned u; float f; } v; v.u = ((unsigned)h) << 16;
  return v.f;
}

__device__ __forceinline__ void gld_lds16(const void* g, void* l) {
  __builtin_amdgcn_global_load_lds(
      (const __attribute__((address_space(1))) unsigned int*)g,
      (__attribute__((address_space(3))) unsigned int*)l, 16, 0, 0);
}

// ---------------- bf16 NT GEMM body, tile TM x TN, BK=64 -------------------
// C[i,j] = sum_k A[i,k]*B[j,k]; A:(M,K), B:(N,K) bf16 row-major.
// LDS rows 128 B = eight 16 B slots; slot s of row r holds global k-chunk
// (s - (r&7)) & 7 -> each 8-lane read phase covers all 32 banks exactly once
// (R10: conflicts 4.9e6 -> 2.3e5).
// MODE 0: bf16 out. MODE 1: f32 out. MODE 4 (128x128): bf16 out + per-col
// softmax partial stats over the block's 128 rows.
template <int MODE, int TM, int TN>
__device__ __forceinline__ void gemm_body(
    const unsigned short* __restrict__ A, const unsigned short* __restrict__ B,
    void* __restrict__ Cout, int K, int lda, int ldb, int ldc, int bi, int bj,
    float* __restrict__ pmax, float* __restrict__ psum) {
  constexpr int FI = TM / 32, FJ = TN / 32;  // frags per wave
  __shared__ unsigned short sA[TM * 64];
  __shared__ unsigned short sB[TN * 64];
  const int tid = threadIdx.x;
  const int wave = tid >> 6;
  const int lane = tid & 63;
  const long i0 = (long)bi * TM;
  const long j0 = (long)bj * TN;
  const int wm = (wave & 1) * (TM / 2);
  const int wn = (wave >> 1) * (TN / 2);

  f32x4 acc[FI][FJ] = {};

  const int srow8 = lane >> 3;              // row within 8-row gld chunk
  const int gk = ((lane & 7) - srow8) & 7;  // staged global k-chunk
  const int mrow = lane & 15;
  const int q2 = lane >> 4;                 // 0..3

  for (int k0 = 0; k0 < K; k0 += 64) {
    __syncthreads();
#pragma unroll
    for (int c = 0; c < TM / 32; ++c) {
      const int q = wave * (TM / 32) + c;
      gld_lds16(A + (i0 + q * 8 + srow8) * (long)lda + k0 + gk * 8, &sA[q * 512]);
    }
#pragma unroll
    for (int c = 0; c < TN / 32; ++c) {
      const int q = wave * (TN / 32) + c;
      gld_lds16(B + (j0 + q * 8 + srow8) * (long)ldb + k0 + gk * 8, &sB[q * 512]);
    }
    __syncthreads();
#pragma unroll
    for (int kk = 0; kk < 2; ++kk) {
      const int slot = ((kk * 4 + q2) + mrow) & 7;
      bf16x8 af[FI], bfr[FJ];
#pragma unroll
      for (int i = 0; i < FI; ++i)
        af[i] = *(const bf16x8*)&sA[(wm + i * 16 + mrow) * 64 + slot * 8];
#pragma unroll
      for (int j = 0; j < FJ; ++j)
        bfr[j] = *(const bf16x8*)&sB[(wn + j * 16 + mrow) * 64 + slot * 8];
#pragma unroll
      for (int i = 0; i < FI; ++i)
#pragma unroll
        for (int j = 0; j < FJ; ++j)
          acc[i][j] =
              __builtin_amdgcn_mfma_f32_16x16x32_bf16(af[i], bfr[j], acc[i][j], 0, 0, 0);
    }
  }

  const int lr = (lane >> 4) * 4;
  const int lc = lane & 15;
#pragma unroll
  for (int i = 0; i < FI; ++i) {
#pragma unroll
    for (int j = 0; j < FJ; ++j) {
#pragma unroll
      for (int r = 0; r < 4; ++r) {
        const long row = i0 + wm + i * 16 + lr + r;
        const long col = j0 + wn + j * 16 + lc;
        const float v = acc[i][j][r];
        if (MODE == 1) ((float*)Cout)[row * ldc + col] = v;
        else ((unsigned short*)Cout)[row * ldc + col] = f2bf(v);
      }
    }
  }

  if constexpr (MODE == 4) {
    float* sMax = (float*)sA;  // [128][8]
    float* sSum = (float*)sB;
    const int k8 = (wave & 1) * 4 + (lane >> 4);
    __syncthreads();
#pragma unroll
    for (int j = 0; j < FJ; ++j) {
      float m = -1e30f;
#pragma unroll
      for (int i = 0; i < FI; ++i)
#pragma unroll
        for (int r = 0; r < 4; ++r) m = fmaxf(m, acc[i][j][r]);
      float sv = 0.f;
#pragma unroll
      for (int i = 0; i < FI; ++i)
#pragma unroll
        for (int r = 0; r < 4; ++r) sv += __expf(acc[i][j][r] - m);
      const int c = wn + j * 16 + lc;
      sMax[c * 8 + k8] = m;
      sSum[c * 8 + k8] = sv;
    }
    __syncthreads();
    if (tid < 128) {
      float m = -1e30f;
#pragma unroll
      for (int k = 0; k < 8; ++k) m = fmaxf(m, sMax[tid * 8 + k]);
      float sv = 0.f;
#pragma unroll
      for (int k = 0; k < 8; ++k) sv += sSum[tid * 8 + k] * __expf(sMax[tid * 8 + k] - m);
      pmax[(size_t)bi * CTXN + j0 + tid] = m;
      psum[(size_t)bi * CTXN + j0 + tid] = sv;
    }
  }
}

// XT[m,n] = sum_d QZT[m,d]*ZbT[n,d] (K=1088) + per-col stats. grid (32,32).
__global__ __launch_bounds__(256, 4) void gemm_xt(
    const unsigned short* __restrict__ QZT, const unsigned short* __restrict__ ZbT,
    unsigned short* __restrict__ XT, float* __restrict__ pmax,
    float* __restrict__ psum) {
  gemm_body<4, 128, 128>(QZT, ZbT, XT, KE, DP, DP, CTXN, blockIdx.x, blockIdx.y, pmax,
                         psum);
}

// Merged QZT + PZ dispatch, 1088 blocks (4.25/CU), K=1088, half-tiles.
// R21: PZ output bf16 (MODE 0) — feeds fp8 quantization, bf16 rounding is noise.
__global__ __launch_bounds__(256, 2) void gemm_dual(
    const unsigned short* __restrict__ ZbT, const unsigned short* __restrict__ Qb,
    unsigned short* __restrict__ QZT, const unsigned short* __restrict__ Pb,
    unsigned short* __restrict__ PZb) {
  const unsigned g = blockIdx.x;
  if (g < 544) {
    gemm_body<0, 128, 64>(ZbT, Qb, QZT, KE, DP, DP, DP, g & 31, g >> 5, nullptr,
                          nullptr);
  } else {
    const unsigned h = g - 544;
    gemm_body<0, 64, 128>(Pb, ZbT, PZb, KE, DP, DP, CTXN, h >> 5, h & 31, nullptr,
                          nullptr);
  }
}

// ---------------- fp8 NT GEMM, no split-K, BK=128, direct f32 out ----------
// A: PZMb (fp8, x256, rows 0..1087 valid — rows 1025..1087 are true zeros),
// B: ET (fp8). 64x64 tiles, K=4096 in steps of 128 -> 16 MFMA per
// barrier-pair (R20 had 8). LDS 16 KB -> all 1088 blocks still co-resident.
// out = Z + acc/256 (rows < 1025). Same-bj sharers at stride 64 -> one XCD.
__global__ __launch_bounds__(256, 2) void gemm_fp8_final(
    const unsigned char* __restrict__ A, const unsigned char* __restrict__ B,
    const float* __restrict__ Z, float* __restrict__ Out) {
  __shared__ unsigned char sA[2][64 * 64];
  __shared__ unsigned char sB[2][64 * 64];
  const int tid = threadIdx.x;
  const int wave = tid >> 6;
  const int lane = tid & 63;
  const unsigned g = blockIdx.x;
  const unsigned bj = g & 63;  // 64 col tiles of 64
  const unsigned bi = g >> 6;  // 0..16
  const long i0 = (long)bi * 64;
  const long j0 = (long)bj * 64;
  const int wm = (wave & 1) * 32;
  const int wn = (wave >> 1) * 32;

  f32x4 acc[2][2] = {};
  const int srow = lane >> 2;
  const int skc = (((lane & 3) - (lane >> 3)) & 3) * 16;  // swizzled 16B slot
  const int mrow = lane & 15;
  const int slot = ((((lane >> 4) + (mrow >> 1)) & 3)) * 16;

  for (int k0 = 0; k0 < CTXN; k0 += 128) {
    __syncthreads();
#pragma unroll
    for (int h = 0; h < 2; ++h) {
      gld_lds16(A + (i0 + wave * 16 + srow) * (long)CTXN + k0 + h * 64 + skc,
                &sA[h][wave * 1024]);
      gld_lds16(B + (j0 + wave * 16 + srow) * (long)CTXN + k0 + h * 64 + skc,
                &sB[h][wave * 1024]);
    }
    __syncthreads();
#pragma unroll
    for (int h = 0; h < 2; ++h) {
      lx2 af[2], bfr[2];
#pragma unroll
      for (int i = 0; i < 2; ++i)
        af[i] = *(const lx2*)&sA[h][(wm + i * 16 + mrow) * 64 + slot];
#pragma unroll
      for (int j = 0; j < 2; ++j)
        bfr[j] = *(const lx2*)&sB[h][(wn + j * 16 + mrow) * 64 + slot];
#pragma unroll
      for (int i = 0; i < 2; ++i)
#pragma unroll
        for (int j = 0; j < 2; ++j) {
          acc[i][j] = __builtin_amdgcn_mfma_f32_16x16x32_fp8_fp8(af[i].x, bfr[j].x,
                                                                 acc[i][j], 0, 0, 0);
          acc[i][j] = __builtin_amdgcn_mfma_f32_16x16x32_fp8_fp8(af[i].y, bfr[j].y,
                                                                 acc[i][j], 0, 0, 0);
        }
    }
  }

  const int lr = (lane >> 4) * 4;
  const int lc = lane & 15;
#pragma unroll
  for (int i = 0; i < 2; ++i)
#pragma unroll
    for (int j = 0; j < 2; ++j)
#pragma unroll
      for (int r = 0; r < 4; ++r) {
        const long row = i0 + wm + i * 16 + lr + r;
        if (row < DIMN) {
          const size_t o = (size_t)row * CTXN + j0 + wn + j * 16 + lc;
          Out[o] = Z[o] + acc[i][j][r] * 0.00390625f;
        }
      }
}

// Merged prep: ids [0,4352) transpose Z -> ZbT (e < 1088 only; rest unused);
// ids [4352, 6944) pad Q/P -> Qb/Pb bf16 (full 1152x1152, zeros outside).
__global__ void prep_kernel(const float* __restrict__ Z, const float* __restrict__ Q,
                            const float* __restrict__ P,
                            unsigned short* __restrict__ ZbT,
                            unsigned short* __restrict__ Qb,
                            unsigned short* __restrict__ Pb) {
  __shared__ float tile[32][33];
  const unsigned g = blockIdx.x;
  const int tid = threadIdx.x;
  if (g < 4352) {
    const int n0 = (g & 127) * 32, e0 = (g >> 7) * 32;  // e0 < 1088
    const int tx = tid & 31, ty = tid >> 5;
#pragma unroll
    for (int k = 0; k < 4; ++k) {
      const int e = e0 + ty + k * 8;
      tile[ty + k * 8][tx] = (e < DIMN) ? Z[(size_t)e * CTXN + n0 + tx] : 0.f;
    }
    __syncthreads();
#pragma unroll
    for (int k = 0; k < 4; ++k) {
      const int n = n0 + ty + k * 8;
      ZbT[(size_t)n * DP + e0 + tx] = f2bf(tile[tx][ty + k * 8]);
    }
  } else {
    const unsigned id2 = g - 4352;  // [0, 2592)
    const int mat = id2 >= 1296;
    const float* src = mat ? P : Q;
    unsigned short* dst = mat ? Pb : Qb;
    const unsigned e0 = (id2 - (mat ? 1296u : 0u)) * 1024u + tid * 4u;
    const unsigned r = e0 / 1152u;
    const unsigned c = e0 - r * 1152u;
    ushort4 o;
    o.x = (r < DIMN && c + 0 < DIMN) ? f2bf(src[(size_t)r * DIMN + c + 0]) : 0;
    o.y = (r < DIMN && c + 1 < DIMN) ? f2bf(src[(size_t)r * DIMN + c + 1]) : 0;
    o.z = (r < DIMN && c + 2 < DIMN) ? f2bf(src[(size_t)r * DIMN + c + 2]) : 0;
    o.w = (r < DIMN && c + 3 < DIMN) ? f2bf(src[(size_t)r * DIMN + c + 3]) : 0;
    *(ushort4*)&dst[(size_t)r * DP + c] = o;
  }
}

// merge 32 chunk stats -> rowmax[n], inv_l[n] = 1/(N*l[n])
__global__ void red2_kernel(const float* __restrict__ pmax, const float* __restrict__ psum,
                            float* __restrict__ rowmax, float* __restrict__ inv_l) {
  const int n = blockIdx.x * 256 + threadIdx.x;
  float M = -1e30f;
  for (int c = 0; c < 32; ++c) M = fmaxf(M, pmax[(size_t)c * CTXN + n]);
  float s = 0.f;
  for (int c = 0; c < 32; ++c)
    s += psum[(size_t)c * CTXN + n] * __expf(pmax[(size_t)c * CTXN + n] - M);
  rowmax[n] = M;
  inv_l[n] = 1.0f / (4095.0f * s);
}

// Merged ew + scan. ids [0,1088): suffix lambda-scan of PZb (bf16) row d ->
// PZMb fp8 x256. ids [1088, 17472): ET[m][n] = fp8(exp(XT[m][n]-rowmax[n])).
__global__ __launch_bounds__(256) void ewscan_kernel(
    const unsigned short* __restrict__ XT, const float* __restrict__ rowmax,
    unsigned int* __restrict__ ET, const unsigned short* __restrict__ PZb,
    const float* __restrict__ inv_l, unsigned char* __restrict__ PZMb) {
  __shared__ float sF[256];
  const unsigned g = blockIdx.x;
  const int t = threadIdx.x;
  if (g >= 1088) {
    const size_t idx = ((size_t)(g - 1088) * 256 + t) * 4;
    const ushort4 v = *(const ushort4*)&XT[idx];
    const int n = (int)(idx & 4095);
    const float4 rm = *(const float4*)&rowmax[n];
    unsigned p = __builtin_amdgcn_cvt_pk_fp8_f32(__expf(bf2f(v.x) - rm.x),
                                                 __expf(bf2f(v.y) - rm.y), 0, false);
    p = __builtin_amdgcn_cvt_pk_fp8_f32(__expf(bf2f(v.z) - rm.z),
                                        __expf(bf2f(v.w) - rm.w), p, true);
    ET[idx >> 2] = p;
    return;
  }
  const int d = g;
  const unsigned short* row = PZb + (size_t)d * CTXN;
  float x[16];
#pragma unroll
  for (int q = 0; q < 4; ++q) {
    const ushort4 v = *(const ushort4*)&row[t * 16 + q * 4];
    x[q * 4 + 0] = bf2f(v.x); x[q * 4 + 1] = bf2f(v.y);
    x[q * 4 + 2] = bf2f(v.z); x[q * 4 + 3] = bf2f(v.w);
  }
  if (t == 255) x[15] = 0.f;  // last row/col of M are zero
  float loc[16];
  float run = 0.f;
#pragma unroll
  for (int i = 15; i >= 0; --i) { run = run * LMBD + x[i]; loc[i] = run; }
  float f = loc[0];
  sF[t] = f;
  __syncthreads();
  float mlt = 0.1853020188851841f;  // lambda^16
  for (int step = 1; step < 256; step <<= 1) {
    const float other = (t + step < 256) ? sF[t + step] : 0.f;
    __syncthreads();
    f += mlt * other;
    mlt *= mlt;
    sF[t] = f;
    __syncthreads();
  }
  const float R = (t < 255) ? sF[t + 1] : 0.f;
  float il[16];
#pragma unroll
  for (int q = 0; q < 4; ++q) {
    const float4 v = *(const float4*)&inv_l[t * 16 + q * 4];
    il[q * 4 + 0] = v.x * 256.f; il[q * 4 + 1] = v.y * 256.f;
    il[q * 4 + 2] = v.z * 256.f; il[q * 4 + 3] = v.w * 256.f;
  }
  float o[16];
  float p = 1.f;
#pragma unroll
  for (int i = 15; i >= 0; --i) {
    p *= LMBD;
    o[i] = (loc[i] + p * R) * il[i];
  }
  unsigned w[4];
#pragma unroll
  for (int q = 0; q < 4; ++q) {
    unsigned pk = __builtin_amdgcn_cvt_pk_fp8_f32(o[q * 4 + 0], o[q * 4 + 1], 0, false);
    pk = __builtin_amdgcn_cvt_pk_fp8_f32(o[q * 4 + 2], o[q * 4 + 3], pk, true);
    w[q] = pk;
  }
  *(uint4*)&PZMb[(size_t)d * CTXN + t * 16] = make_uint4(w[0], w[1], w[2], w[3]);
}

extern "C" void kernel_launch(void* const* d_in, const int* in_sizes, int n_in,
                              void* d_out, int out_size, void* d_ws, size_t ws_size,
                              hipStream_t stream) {
  const float* Z = (const float*)d_in[0];
  const float* P = (const float*)d_in[1];
  const float* Q = (const float*)d_in[2];
  // d_in[3] = M: reproduced analytically by the scan.

  char* ws = (char*)d_ws;
  size_t off = 0;
  auto alloc = [&](size_t bytes) {
    void* p = ws + off;
    off += (bytes + 255) & ~(size_t)255;
    return p;
  };
  // persistent through the final GEMM:
  unsigned char* ET   = (unsigned char*)alloc((size_t)CTXN * CTXN);  // fp8
  unsigned char* PZMb = (unsigned char*)alloc((size_t)DP * CTXN);    // fp8 x256
  float* rowmax       = (float*)alloc((size_t)CTXN * 4);
  float* inv_l        = (float*)alloc((size_t)CTXN * 4);
  unsigned short* ZbT = (unsigned short*)alloc((size_t)CTXN * DP * 2);
  unsigned short* QZT = (unsigned short*)alloc((size_t)CTXN * DP * 2);
  unsigned short* XT  = (unsigned short*)alloc((size_t)CTXN * CTXN * 2);
  unsigned short* PZb = (unsigned short*)alloc((size_t)DP * CTXN * 2);  // bf16
  unsigned short* Qb  = (unsigned short*)alloc((size_t)DP * DP * 2);
  unsigned short* Pb  = (unsigned short*)alloc((size_t)DP * DP * 2);
  float* pmax         = (float*)alloc((size_t)32 * CTXN * 4);
  float* psum         = (float*)alloc((size_t)32 * CTXN * 4);
  if (off > ws_size) return;

  // Z transpose (e < 1088) + Q/P pad, one dispatch
  prep_kernel<<<6944, 256, 0, stream>>>(Z, Q, P, ZbT, Qb, Pb);

  // QZT[m,d] and PZb[d,n] (bf16) in one dispatch, K=1088, half-tiles
  gemm_dual<<<1088, 256, 0, stream>>>(ZbT, Qb, QZT, Pb, PZb);

  // XT[m,n] = sum_d QZT[m,d] * ZbT[n,d], K=1088; epilogue: per-col stats
  gemm_xt<<<dim3(32, 32), 256, 0, stream>>>(QZT, ZbT, XT, pmax, psum);

  red2_kernel<<<16, 256, 0, stream>>>(pmax, psum, rowmax, inv_l);

  // scan (PZb rows < 1088 -> PZMb fp8 x256) + ew (XT -> ET fp8), one dispatch
  ewscan_kernel<<<17472, 256, 0, stream>>>(XT, rowmax, (unsigned int*)ET, PZb, inv_l,
                                           PZMb);

  // out = Z + (PZMb @ ET^T)/256, no split-K, BK=128, direct f32 (rows < 1025)
  gemm_fp8_final<<<1088, 256, 0, stream>>>(PZMb, ET, Z, (float*)d_out);
}